// Round 10
// baseline (146.479 us; speedup 1.0000x reference)
//
#include <hip/hip_runtime.h>
#include <hip/hip_bf16.h>

// out = bias + sum_i sum_m quadratic forms (K_m folded into quad stage).
// accum stores UNSCALED c': c'[slot] = sum_edges t_m(d)*r^(n-k)*gauss*fc
//   t_m(d) = {1, dy, dz, dx, dxdy, dydz, dz^2-u/3, dxdz, dx^2-dy^2}
// c2 layout: c2[atom][slot], slot = m*36 + a*12 + n  (bf16, 324/atom)
// bucket: 4 sharded sub-buckets of 32 per atom (128 ints); UNFILTERED edges,
// r2-filter applied in accum's valid mask.

#define NT 3
#define CPA 324
#define A_ELEMS 3888
#define WPB 4      // waves per block in accum

typedef __attribute__((ext_vector_type(4))) unsigned short ushort4v;
typedef unsigned long long ull;

#if __has_builtin(__builtin_amdgcn_exp2f)
__device__ __forceinline__ float exp2_fast(float x) { return __builtin_amdgcn_exp2f(x); }
#else
__device__ __forceinline__ float exp2_fast(float x) { return __expf(x * 0.6931471805599453f); }
#endif

__global__ void prep_kernel(const float* __restrict__ w,
                            const float* __restrict__ bias,
                            const float* __restrict__ pos,
                            const int* __restrict__ types,
                            float* __restrict__ A,
                            float4* __restrict__ posT,
                            int4* __restrict__ cnt4,
                            float* __restrict__ out, int N) {
    int t = blockIdx.x * blockDim.x + threadIdx.x;
    if (t == 0) out[0] = bias[0];
    if (t < A_ELEMS) {
        int l   = t / 1296;
        int rem = t - l * 1296;
        int an  = rem / 36;
        int bk  = rem - an * 36;
        int a = an / 12, n = an - (an / 12) * 12;
        int b = bk / 12, k = bk - (bk / 12) * 12;
        float inv = (l == 0) ? 1.0f : (l == 1 ? 0.57735026918962576f
                                              : 0.44721359549995794f);
        A[t] = w[a * 1296 + n * 108 + b * 36 + k * 3 + l] * inv;
    }
    if (t < N) {
        float4 p;
        p.x = pos[3 * t + 0];
        p.y = pos[3 * t + 1];
        p.z = pos[3 * t + 2];
        p.w = __int_as_float(types[t]);
        posT[t] = p;
        cnt4[t] = make_int4(0, 0, 0, 0);
    }
}

// Pure-int bucket build: no gathers, no filter, 4-way sharded cursors.
__global__ void build_kernel(const int* __restrict__ pairs,
                             int* __restrict__ cnt,
                             int* __restrict__ bucket, int E) {
    int t = blockIdx.x * blockDim.x + threadIdx.x;
    int e0 = t << 1;
    if (e0 >= E) return;
    if (e0 + 1 < E) {
        int4 p4 = ((const int4*)pairs)[t];
        int s0 = e0 & 3, s1 = (e0 + 1) & 3;
        int p = atomicAdd(&cnt[(p4.x << 2) + s0], 1);
        if (p < 32) bucket[(p4.x << 7) + (s0 << 5) + p] = p4.y;
        int q = atomicAdd(&cnt[(p4.z << 2) + s1], 1);
        if (q < 32) bucket[(p4.z << 7) + (s1 << 5) + q] = p4.w;
    } else {
        int i = pairs[2 * e0], j = pairs[2 * e0 + 1];
        int s0 = e0 & 3;
        int p = atomicAdd(&cnt[(i << 2) + s0], 1);
        if (p < 32) bucket[(i << 7) + (s0 << 5) + p] = j;
    }
}

// One wave per atom. Prologue: lane k maps to its sharded bucket slot,
// gathers neighbor, computes geometry + 9 polynomial numerators, filters
// (r2<12.96) and type-sorts via ballots, writes 16-float record to LDS.
// Edge loop: per slot = 1 lane-indexed ds_read (t_m) + 2 fma + exp2 + fma.
__global__ void __launch_bounds__(256)
accum_kernel(const float4* __restrict__ posT,
             const int4* __restrict__ cnt4,
             const int* __restrict__ bucket,
             __hip_bfloat16* __restrict__ c2, int N) {
    __shared__ float sE[WPB][64][16];
    int wid = (blockIdx.x * blockDim.x + threadIdx.x) >> 6;
    int lane = threadIdx.x & 63;
    int wslot = (threadIdx.x >> 6);
    if (wid >= N) return;
    int i = wid;

    float4 pi = posT[i];
    int4 c4 = cnt4[i];
    int d0 = min(c4.x, 32), d1 = min(c4.y, 32), d2 = min(c4.z, 32), d3 = min(c4.w, 32);
    int b1 = d0, b2 = d0 + d1, b3 = b2 + d2;
    int degt = min(b3 + d3, 64);
    int deg = __builtin_amdgcn_readfirstlane(degt);

    // lane -> (shard, offset) in sharded bucket row
    int k = lane;
    int seg  = (k >= b1) + (k >= b2) + (k >= b3);
    int base = seg == 0 ? 0 : (seg == 1 ? b1 : (seg == 2 ? b2 : b3));
    int slot = (seg << 5) + (k - base);
    int jv = bucket[(i << 7) + slot];
    bool inb = k < deg;
    int jsafe = inb ? jv : i;
    float4 pj = posT[jsafe];

    float dx = pj.x - pi.x, dy = pj.y - pi.y, dz = pj.z - pi.z;
    float u  = fmaf(dz, dz, fmaf(dy, dy, fmaf(dx, dx, 1e-12f)));
    bool valid = inb && (u < 12.96f);
    float wv = __log2f(u);
    float lf = 0.0f;
    if (u >= 10.89f) {                        // 3.3 <= r: taper folded into exp
        float r = sqrtf(u);
        float fcv = 0.5f + 0.5f * __cosf(10.471975511965978f * (r - 3.3f));
        lf = __log2f(fcv);
    }
    int tj = __float_as_int(pj.w);

    // polynomial numerators
    float t4 = dx * dy, t5 = dy * dz, t7 = dx * dz;
    float t6 = fmaf(dz, dz, -0.33333333333333333f * u);
    float t8 = fmaf(dx, dx, -(dy * dy));

    // type-sort among valid lanes
    ull m0b = __ballot(valid && tj == 0);
    ull m1b = __ballot(valid && tj == 1);
    ull m2b = __ballot(valid && tj == 2);
    ull lt  = (lane == 63) ? 0x7FFFFFFFFFFFFFFFull : ((1ull << lane) - 1ull);
    int c0n = __popcll(m0b);
    int c1n = __popcll(m1b);
    int nval = c0n + c1n + __popcll(m2b);
    int dest;
    if (!valid)          dest = nval + __popcll(~(m0b | m1b | m2b) & lt);
    else if (tj == 0)    dest = __popcll(m0b & lt);
    else if (tj == 1)    dest = c0n + __popcll(m1b & lt);
    else                 dest = c0n + c1n + __popcll(m2b & lt);

    float* rec = &sE[wslot][dest][0];
    ((float4*)rec)[0] = make_float4(u, wv, lf, 0.0f);
    ((float4*)rec)[1] = make_float4(1.0f, dy, dz, dx);
    ((float4*)rec)[2] = make_float4(t4, t5, t6, t7);
    ((float4*)rec)[3] = make_float4(t8, 0.0f, 0.0f, 0.0f);
    asm volatile("s_waitcnt lgkmcnt(0)" ::: "memory");

    int e1b = c0n + c1n;     // scalar (ballot popcounts)

    // per-lane radial constants for slots lane and lane+64
    int n0 = lane % 12, m0 = lane / 12;
    int idx1 = lane + 64;
    bool has1 = idx1 < 108;
    int i1 = has1 ? idx1 : 0;
    int n1 = i1 % 12, m1 = i1 / 12;
    float fn0 = (float)n0, fn1 = (float)n1;
    float sg0 = 0.3f * fmaxf(sqrtf(fn0), 1.0f);
    float sg1 = 0.3f * fmaxf(sqrtf(fn1), 1.0f);
    float qc0 = -0.5f / (sg0 * sg0) * 1.4426950408889634f;
    float qc1 = -0.5f / (sg1 * sg1) * 1.4426950408889634f;
    int k0 = (m0 == 0) ? 0 : (m0 < 4 ? 1 : 2);
    int k1 = (m1 == 0) ? 0 : (m1 < 4 ? 1 : 2);
    float fnp0 = 0.5f * (fn0 - (float)k0);
    float fnp1 = 0.5f * (fn1 - (float)k1);

    const float* recb = &sE[wslot][0][0];
    const float* tp0 = recb + 4 + m0;    // lane-indexed poly ptr, slot0
    const float* tp1 = recb + 4 + m1;    // slot1

    float a00 = 0.f, a01 = 0.f, a02 = 0.f;
    float a10 = 0.f, a11 = 0.f, a12 = 0.f;

    #define EDGE_BODY(E_IDX, ACC0, ACC1)                                   \
    {                                                                      \
        int off = (E_IDX) << 4;                                            \
        float su  = recb[off + 0];                                         \
        float sw  = recb[off + 1];                                         \
        float slf = recb[off + 2];                                         \
        float tm0 = tp0[off];                                              \
        float tm1 = tp1[off];                                              \
        float rad0 = exp2_fast(fmaf(fnp0, sw, fmaf(qc0, su, slf)));        \
        float rad1 = exp2_fast(fmaf(fnp1, sw, fmaf(qc1, su, slf)));        \
        ACC0 = fmaf(rad0, tm0, ACC0);                                      \
        ACC1 = fmaf(rad1, tm1, ACC1);                                      \
    }

    int e = 0;
    #pragma unroll 2
    for (; e < c0n; ++e)  EDGE_BODY(e, a00, a10);
    #pragma unroll 2
    for (; e < e1b; ++e)  EDGE_BODY(e, a01, a11);
    #pragma unroll 2
    for (; e < nval; ++e) EDGE_BODY(e, a02, a12);
    #undef EDGE_BODY

    __hip_bfloat16* cb = c2 + (size_t)i * CPA;
    cb[m0 * 36 + 0 * 12 + n0] = __float2bfloat16(a00);
    cb[m0 * 36 + 1 * 12 + n0] = __float2bfloat16(a01);
    cb[m0 * 36 + 2 * 12 + n0] = __float2bfloat16(a02);
    if (has1) {
        cb[m1 * 36 + 0 * 12 + n1] = __float2bfloat16(a10);
        cb[m1 * 36 + 1 * 12 + n1] = __float2bfloat16(a11);
        cb[m1 * 36 + 2 * 12 + n1] = __float2bfloat16(a12);
    }
}

// Wave = (64 atoms, one m). Rescale v by K_m, add Y00 self-term, v^T A_l v.
__global__ void __launch_bounds__(576)
quad_kernel(const __hip_bfloat16* __restrict__ c2,
            const int* __restrict__ types,
            const float* __restrict__ A,
            float* __restrict__ out, int N) {
    __shared__ float sred[9];
    int m = __builtin_amdgcn_readfirstlane(threadIdx.x >> 6);
    int lane = threadIdx.x & 63;
    int i = blockIdx.x * 64 + lane;
    float dot = 0.0f;
    if (i < N) {
        float Km = m == 0 ? 0.28209479177387814f
                 : (m < 4 ? 0.4886025119029199f
                 : (m == 6 ? 0.94617469575756f
                 : (m == 8 ? 0.5462742152960396f : 1.0925484305920792f)));
        const ushort4v* cb4 =
            (const ushort4v*)(c2 + (size_t)i * CPA + m * 36);
        float v[36];
        #pragma unroll
        for (int q = 0; q < 9; ++q) {
            ushort4v u = cb4[q];
            #pragma unroll
            for (int r = 0; r < 4; ++r)
                v[q * 4 + r] = __uint_as_float(((unsigned)u[r]) << 16) * Km;
        }
        if (m == 0) {
            int ti = types[i];
            const float Y00 = 0.28209479177387814f;
            v[0]  += ti == 0 ? Y00 : 0.f;
            v[12] += ti == 1 ? Y00 : 0.f;
            v[24] += ti == 2 ? Y00 : 0.f;
        }
        int l = (m == 0) ? 0 : (m < 4 ? 1 : 2);
        const float* Al = A + l * 1296;
        #pragma unroll
        for (int an = 0; an < 36; ++an) {
            float s = 0.0f;
            #pragma unroll
            for (int b = 0; b < 36; ++b)
                s = fmaf(Al[an * 36 + b], v[b], s);
            dot = fmaf(v[an], s, dot);
        }
    }
    #pragma unroll
    for (int off = 32; off > 0; off >>= 1) dot += __shfl_down(dot, off, 64);
    if (lane == 0) sred[m] = dot;
    __syncthreads();
    if (threadIdx.x == 0) {
        float s = 0.f;
        #pragma unroll
        for (int kk = 0; kk < 9; ++kk) s += sred[kk];
        atomicAdd(out, s);
    }
}

extern "C" void kernel_launch(void* const* d_in, const int* in_sizes, int n_in,
                              void* d_out, int out_size, void* d_ws, size_t ws_size,
                              hipStream_t stream) {
    const float* pos   = (const float*)d_in[0];
    const float* w     = (const float*)d_in[1];
    const float* bias  = (const float*)d_in[2];
    const int*   types = (const int*)d_in[3];
    const int*   pairs = (const int*)d_in[4];
    float* out = (float*)d_out;

    int N = in_sizes[0] / 3;
    int E = in_sizes[4] / 2;

    char* ws = (char*)d_ws;
    size_t off = 0;
    float* A = (float*)(ws + off);            off += 16384;
    int* cnt = (int*)(ws + off);              off += ((size_t)N * 16 + 255) & ~(size_t)255;
    float4* posT = (float4*)(ws + off);       off += ((size_t)N * 16 + 255) & ~(size_t)255;
    int* bucket = (int*)(ws + off);           off += ((size_t)N * 128 * 4 + 255) & ~(size_t)255;
    __hip_bfloat16* c2 = (__hip_bfloat16*)(ws + off);

    int pblocks = (N + 255) / 256;
    prep_kernel<<<pblocks, 256, 0, stream>>>(w, bias, pos, types, A, posT,
                                             (int4*)cnt, out, N);

    int ehalf = (E + 1) / 2;
    int eblocks = (ehalf + 255) / 256;
    build_kernel<<<eblocks, 256, 0, stream>>>(pairs, cnt, bucket, E);

    int ablocks = ((size_t)N * 64 + 255) / 256;
    accum_kernel<<<ablocks, 256, 0, stream>>>(posT, (const int4*)cnt, bucket, c2, N);

    int qblocks = (N + 63) / 64;
    quad_kernel<<<qblocks, 576, 0, stream>>>(c2, types, A, out, N);
}

// Round 11
// 103.428 us; speedup vs baseline: 1.4162x; 1.4162x over previous
//
#include <hip/hip_runtime.h>
#include <hip/hip_bf16.h>

// out = bias + sum_i sum_m quadratic forms (K_m folded into quad stage).
// accum stores UNSCALED c': c'[slot] = sum_edges t_m(d)*r^(n-k)*gauss*fc
//   t_m(d) = {1, dy, dz, dx, dxdy, dydz, dz^2-u/3, dxdz, dx^2-dy^2}
// c2 layout: c2[atom][slot], slot = m*36 + a*12 + n  (bf16, 324/atom)
// bucket: 64 uint16 entries per atom (filtered edges only).

#define NT 3
#define CPA 324
#define A_ELEMS 3888
#define BCAP 64
#define WPB 4      // waves per block in accum

typedef __attribute__((ext_vector_type(4))) unsigned short ushort4v;
typedef unsigned long long ull;

#if __has_builtin(__builtin_amdgcn_exp2f)
__device__ __forceinline__ float exp2_fast(float x) { return __builtin_amdgcn_exp2f(x); }
#else
__device__ __forceinline__ float exp2_fast(float x) { return __expf(x * 0.6931471805599453f); }
#endif

__global__ void prep_kernel(const float* __restrict__ w,
                            const float* __restrict__ bias,
                            const float* __restrict__ pos,
                            const int* __restrict__ types,
                            float* __restrict__ A,
                            float4* __restrict__ posT,
                            int* __restrict__ cnt,
                            float* __restrict__ out, int N) {
    int t = blockIdx.x * blockDim.x + threadIdx.x;
    if (t == 0) out[0] = bias[0];
    if (t < A_ELEMS) {
        int l   = t / 1296;
        int rem = t - l * 1296;
        int an  = rem / 36;
        int bk  = rem - an * 36;
        int a = an / 12, n = an - (an / 12) * 12;
        int b = bk / 12, k = bk - (bk / 12) * 12;
        float inv = (l == 0) ? 1.0f : (l == 1 ? 0.57735026918962576f
                                              : 0.44721359549995794f);
        A[t] = w[a * 1296 + n * 108 + b * 36 + k * 3 + l] * inv;
    }
    if (t < N) {
        float4 p;
        p.x = pos[3 * t + 0];
        p.y = pos[3 * t + 1];
        p.z = pos[3 * t + 2];
        p.w = __int_as_float(types[t]);
        posT[t] = p;
        cnt[t] = 0;
    }
}

// Filtered bucket build; uint16 entries (j < 65536), 2 edges/thread.
__global__ void build_kernel(const int* __restrict__ pairs,
                             const float4* __restrict__ posT,
                             int* __restrict__ cnt,
                             unsigned short* __restrict__ bucket, int E) {
    int t = blockIdx.x * blockDim.x + threadIdx.x;
    int e0 = t << 1;
    if (e0 >= E) return;
    int pi0, pj0, pi1 = 0, pj1 = 0;
    bool two = (e0 + 1) < E;
    if (two) {
        int4 p4 = ((const int4*)pairs)[t];
        pi0 = p4.x; pj0 = p4.y; pi1 = p4.z; pj1 = p4.w;
    } else {
        pi0 = pairs[2 * e0]; pj0 = pairs[2 * e0 + 1];
    }
    {
        float4 a = posT[pi0], b = posT[pj0];
        float dx = b.x - a.x, dy = b.y - a.y, dz = b.z - a.z;
        float r2 = dx * dx + dy * dy + dz * dz;
        if (r2 < 12.96f) {
            int p = atomicAdd(&cnt[pi0], 1);
            if (p < BCAP) bucket[(pi0 << 6) + p] = (unsigned short)pj0;
        }
    }
    if (two) {
        float4 a = posT[pi1], b = posT[pj1];
        float dx = b.x - a.x, dy = b.y - a.y, dz = b.z - a.z;
        float r2 = dx * dx + dy * dy + dz * dz;
        if (r2 < 12.96f) {
            int p = atomicAdd(&cnt[pi1], 1);
            if (p < BCAP) bucket[(pi1 << 6) + p] = (unsigned short)pj1;
        }
    }
}

// One wave per atom. Prologue: lane k gathers its edge's neighbor, computes
// geometry + 9 polynomial numerators, type-sorts via ballots, writes a
// 16-float record to LDS. Edge loop per slot: lane-indexed ds_read of t_m +
// exp2 radial + acc fma. No per-edge branches or readlanes.
__global__ void __launch_bounds__(256)
accum_kernel(const float4* __restrict__ posT,
             const int* __restrict__ cnt,
             const unsigned short* __restrict__ bucket,
             __hip_bfloat16* __restrict__ c2, int N) {
    __shared__ float sE[WPB][64][16];
    int wid = (blockIdx.x * blockDim.x + threadIdx.x) >> 6;
    int lane = threadIdx.x & 63;
    int wslot = (threadIdx.x >> 6);
    if (wid >= N) return;
    int i = wid;

    float4 pi = posT[i];
    int degv = cnt[i];
    degv = degv > BCAP ? BCAP : degv;
    int deg = __builtin_amdgcn_readfirstlane(degv);

    int jv = bucket[(i << 6) + lane];        // coalesced 128B row
    bool valid = lane < deg;
    int jsafe = valid ? jv : i;              // guard stale (poisoned) slots
    float4 pj = posT[jsafe];

    float dx = pj.x - pi.x, dy = pj.y - pi.y, dz = pj.z - pi.z;
    float u  = fmaf(dz, dz, fmaf(dy, dy, fmaf(dx, dx, 1e-12f)));
    float wv = __log2f(u);
    float lf = 0.0f;
    if (u >= 10.89f) {                       // 3.3 <= r < 3.6: taper into exp
        float r = sqrtf(u);
        float fcv = 0.5f + 0.5f * __cosf(10.471975511965978f * (r - 3.3f));
        lf = __log2f(fcv);
    }
    int tj = __float_as_int(pj.w);

    // polynomial numerators
    float t4 = dx * dy, t5 = dy * dz, t7 = dx * dz;
    float t6 = fmaf(dz, dz, -0.33333333333333333f * u);
    float t8 = fmaf(dx, dx, -(dy * dy));

    // type-sort among valid lanes
    ull m0b = __ballot(valid && tj == 0);
    ull m1b = __ballot(valid && tj == 1);
    ull m2b = __ballot(valid && tj == 2);
    ull lt  = (lane == 63) ? 0x7FFFFFFFFFFFFFFFull : ((1ull << lane) - 1ull);
    int c0n = __popcll(m0b);
    int c1n = __popcll(m1b);
    int dest;
    if (!valid)          dest = deg + __popcll(~(m0b | m1b | m2b) & lt);
    else if (tj == 0)    dest = __popcll(m0b & lt);
    else if (tj == 1)    dest = c0n + __popcll(m1b & lt);
    else                 dest = c0n + c1n + __popcll(m2b & lt);

    float* rec = &sE[wslot][dest][0];
    ((float4*)rec)[0] = make_float4(u, wv, lf, 0.0f);
    ((float4*)rec)[1] = make_float4(1.0f, dy, dz, dx);
    ((float4*)rec)[2] = make_float4(t4, t5, t6, t7);
    ((float4*)rec)[3] = make_float4(t8, 0.0f, 0.0f, 0.0f);
    asm volatile("s_waitcnt lgkmcnt(0)" ::: "memory");

    int e1b = c0n + c1n;                     // scalar (ballot popcounts)

    // per-lane radial constants for slots lane and lane+64
    int n0 = lane % 12, m0 = lane / 12;
    int idx1 = lane + 64;
    bool has1 = idx1 < 108;
    int i1 = has1 ? idx1 : 0;
    int n1 = i1 % 12, m1 = i1 / 12;
    float fn0 = (float)n0, fn1 = (float)n1;
    float sg0 = 0.3f * fmaxf(sqrtf(fn0), 1.0f);
    float sg1 = 0.3f * fmaxf(sqrtf(fn1), 1.0f);
    float qc0 = -0.5f / (sg0 * sg0) * 1.4426950408889634f;
    float qc1 = -0.5f / (sg1 * sg1) * 1.4426950408889634f;
    int k0 = (m0 == 0) ? 0 : (m0 < 4 ? 1 : 2);
    int k1 = (m1 == 0) ? 0 : (m1 < 4 ? 1 : 2);
    float fnp0 = 0.5f * (fn0 - (float)k0);
    float fnp1 = 0.5f * (fn1 - (float)k1);

    const float* recb = &sE[wslot][0][0];
    const float* tp0 = recb + 4 + m0;        // lane-indexed poly ptr, slot0
    const float* tp1 = recb + 4 + m1;        // slot1

    float a00 = 0.f, a01 = 0.f, a02 = 0.f;
    float a10 = 0.f, a11 = 0.f, a12 = 0.f;

    #define EDGE_BODY(E_IDX, ACC0, ACC1)                                   \
    {                                                                      \
        int off = (E_IDX) << 4;                                            \
        float su  = recb[off + 0];                                         \
        float sw  = recb[off + 1];                                         \
        float slf = recb[off + 2];                                         \
        float tm0 = tp0[off];                                              \
        float tm1 = tp1[off];                                              \
        float rad0 = exp2_fast(fmaf(fnp0, sw, fmaf(qc0, su, slf)));        \
        float rad1 = exp2_fast(fmaf(fnp1, sw, fmaf(qc1, su, slf)));        \
        ACC0 = fmaf(rad0, tm0, ACC0);                                      \
        ACC1 = fmaf(rad1, tm1, ACC1);                                      \
    }

    int e = 0;
    #pragma unroll 2
    for (; e < c0n; ++e)  EDGE_BODY(e, a00, a10);
    #pragma unroll 2
    for (; e < e1b; ++e)  EDGE_BODY(e, a01, a11);
    #pragma unroll 2
    for (; e < deg; ++e)  EDGE_BODY(e, a02, a12);
    #undef EDGE_BODY

    __hip_bfloat16* cb = c2 + (size_t)i * CPA;
    cb[m0 * 36 + 0 * 12 + n0] = __float2bfloat16(a00);
    cb[m0 * 36 + 1 * 12 + n0] = __float2bfloat16(a01);
    cb[m0 * 36 + 2 * 12 + n0] = __float2bfloat16(a02);
    if (has1) {
        cb[m1 * 36 + 0 * 12 + n1] = __float2bfloat16(a10);
        cb[m1 * 36 + 1 * 12 + n1] = __float2bfloat16(a11);
        cb[m1 * 36 + 2 * 12 + n1] = __float2bfloat16(a12);
    }
}

// Wave = (64 atoms, one m). Rescale v by K_m, add Y00 self-term, v^T A_l v.
__global__ void __launch_bounds__(576)
quad_kernel(const __hip_bfloat16* __restrict__ c2,
            const int* __restrict__ types,
            const float* __restrict__ A,
            float* __restrict__ out, int N) {
    __shared__ float sred[9];
    int m = __builtin_amdgcn_readfirstlane(threadIdx.x >> 6);
    int lane = threadIdx.x & 63;
    int i = blockIdx.x * 64 + lane;
    float dot = 0.0f;
    if (i < N) {
        float Km = m == 0 ? 0.28209479177387814f
                 : (m < 4 ? 0.4886025119029199f
                 : (m == 6 ? 0.94617469575756f
                 : (m == 8 ? 0.5462742152960396f : 1.0925484305920792f)));
        const ushort4v* cb4 =
            (const ushort4v*)(c2 + (size_t)i * CPA + m * 36);
        float v[36];
        #pragma unroll
        for (int q = 0; q < 9; ++q) {
            ushort4v u = cb4[q];
            #pragma unroll
            for (int r = 0; r < 4; ++r)
                v[q * 4 + r] = __uint_as_float(((unsigned)u[r]) << 16) * Km;
        }
        if (m == 0) {
            int ti = types[i];
            const float Y00 = 0.28209479177387814f;
            v[0]  += ti == 0 ? Y00 : 0.f;
            v[12] += ti == 1 ? Y00 : 0.f;
            v[24] += ti == 2 ? Y00 : 0.f;
        }
        int l = (m == 0) ? 0 : (m < 4 ? 1 : 2);
        const float* Al = A + l * 1296;
        #pragma unroll
        for (int an = 0; an < 36; ++an) {
            float s = 0.0f;
            #pragma unroll
            for (int b = 0; b < 36; ++b)
                s = fmaf(Al[an * 36 + b], v[b], s);
            dot = fmaf(v[an], s, dot);
        }
    }
    #pragma unroll
    for (int off = 32; off > 0; off >>= 1) dot += __shfl_down(dot, off, 64);
    if (lane == 0) sred[m] = dot;
    __syncthreads();
    if (threadIdx.x == 0) {
        float s = 0.f;
        #pragma unroll
        for (int kk = 0; kk < 9; ++kk) s += sred[kk];
        atomicAdd(out, s);
    }
}

extern "C" void kernel_launch(void* const* d_in, const int* in_sizes, int n_in,
                              void* d_out, int out_size, void* d_ws, size_t ws_size,
                              hipStream_t stream) {
    const float* pos   = (const float*)d_in[0];
    const float* w     = (const float*)d_in[1];
    const float* bias  = (const float*)d_in[2];
    const int*   types = (const int*)d_in[3];
    const int*   pairs = (const int*)d_in[4];
    float* out = (float*)d_out;

    int N = in_sizes[0] / 3;
    int E = in_sizes[4] / 2;

    char* ws = (char*)d_ws;
    size_t off = 0;
    float* A = (float*)(ws + off);             off += 16384;
    int* cnt = (int*)(ws + off);               off += ((size_t)N * 4 + 255) & ~(size_t)255;
    float4* posT = (float4*)(ws + off);        off += ((size_t)N * 16 + 255) & ~(size_t)255;
    unsigned short* bucket = (unsigned short*)(ws + off);
                                               off += ((size_t)N * BCAP * 2 + 255) & ~(size_t)255;
    __hip_bfloat16* c2 = (__hip_bfloat16*)(ws + off);

    int pblocks = (N + 255) / 256;
    prep_kernel<<<pblocks, 256, 0, stream>>>(w, bias, pos, types, A, posT, cnt, out, N);

    int ehalf = (E + 1) / 2;
    int eblocks = (ehalf + 255) / 256;
    build_kernel<<<eblocks, 256, 0, stream>>>(pairs, posT, cnt, bucket, E);

    int ablocks = ((size_t)N * 64 + 255) / 256;
    accum_kernel<<<ablocks, 256, 0, stream>>>(posT, cnt, bucket, c2, N);

    int qblocks = (N + 63) / 64;
    quad_kernel<<<qblocks, 576, 0, stream>>>(c2, types, A, out, N);
}

// Round 12
// 94.671 us; speedup vs baseline: 1.5472x; 1.0925x over previous
//
#include <hip/hip_runtime.h>
#include <hip/hip_bf16.h>

// out = bias + sum_i sum_m quadratic forms (K_m folded into quad stage).
// accum: per edge, c'[m][n] += T_m * R_n  (rank-1 outer product), where
//   R_n = r^n * exp(-0.5 (r/sigma_n)^2) * fc   (12 exp2, prologue)
//   T_m = t_m * r^(-k(m)),  t_m = {1,dy,dz,dx,dxdy,dydz,dz^2-u/3,dxdz,dx^2-dy^2}
// c2 layout: c2[atom][slot], slot = m*36 + a*12 + n  (bf16, 324/atom)
// bucket: 64 uint16 entries per atom (filtered edges only).

#define NT 3
#define CPA 324
#define A_ELEMS 3888
#define BCAP 64
#define WPB 4        // waves per block in accum
#define RSTRIDE 25   // record stride in floats (odd -> conflict-free)

typedef __attribute__((ext_vector_type(4))) unsigned short ushort4v;
typedef unsigned long long ull;

#if __has_builtin(__builtin_amdgcn_exp2f)
__device__ __forceinline__ float exp2_fast(float x) { return __builtin_amdgcn_exp2f(x); }
#else
__device__ __forceinline__ float exp2_fast(float x) { return __expf(x * 0.6931471805599453f); }
#endif

__global__ void prep_kernel(const float* __restrict__ w,
                            const float* __restrict__ bias,
                            const float* __restrict__ pos,
                            const int* __restrict__ types,
                            float* __restrict__ A,
                            float4* __restrict__ posT,
                            int* __restrict__ cnt,
                            float* __restrict__ out, int N) {
    int t = blockIdx.x * blockDim.x + threadIdx.x;
    if (t == 0) out[0] = bias[0];
    if (t < A_ELEMS) {
        int l   = t / 1296;
        int rem = t - l * 1296;
        int an  = rem / 36;
        int bk  = rem - an * 36;
        int a = an / 12, n = an - (an / 12) * 12;
        int b = bk / 12, k = bk - (bk / 12) * 12;
        float inv = (l == 0) ? 1.0f : (l == 1 ? 0.57735026918962576f
                                              : 0.44721359549995794f);
        A[t] = w[a * 1296 + n * 108 + b * 36 + k * 3 + l] * inv;
    }
    if (t < N) {
        float4 p;
        p.x = pos[3 * t + 0];
        p.y = pos[3 * t + 1];
        p.z = pos[3 * t + 2];
        p.w = __int_as_float(types[t]);
        posT[t] = p;
        cnt[t] = 0;
    }
}

__device__ __forceinline__ void build_one(int i, int j,
                                          const float4& a, const float4& b,
                                          int* cnt, unsigned short* bucket) {
    float dx = b.x - a.x, dy = b.y - a.y, dz = b.z - a.z;
    float r2 = dx * dx + dy * dy + dz * dz;
    if (r2 < 12.96f) {
        int p = atomicAdd(&cnt[i], 1);
        if (p < BCAP) bucket[(i << 6) + p] = (unsigned short)j;
    }
}

// Filtered bucket build; uint16 entries; 4 edges/thread, gathers batched for MLP.
__global__ void build_kernel(const int* __restrict__ pairs,
                             const float4* __restrict__ posT,
                             int* __restrict__ cnt,
                             unsigned short* __restrict__ bucket, int E) {
    int t = blockIdx.x * blockDim.x + threadIdx.x;
    int e0 = t << 2;
    if (e0 >= E) return;
    if (e0 + 4 <= E) {
        int4 q0 = ((const int4*)pairs)[t * 2];
        int4 q1 = ((const int4*)pairs)[t * 2 + 1];
        float4 a0 = posT[q0.x], b0 = posT[q0.y];
        float4 a1 = posT[q0.z], b1 = posT[q0.w];
        float4 a2 = posT[q1.x], b2 = posT[q1.y];
        float4 a3 = posT[q1.z], b3 = posT[q1.w];
        build_one(q0.x, q0.y, a0, b0, cnt, bucket);
        build_one(q0.z, q0.w, a1, b1, cnt, bucket);
        build_one(q1.x, q1.y, a2, b2, cnt, bucket);
        build_one(q1.z, q1.w, a3, b3, cnt, bucket);
    } else {
        for (int e = e0; e < E; ++e) {
            int i = pairs[2 * e], j = pairs[2 * e + 1];
            float4 a = posT[i], b = posT[j];
            build_one(i, j, a, b, cnt, bucket);
        }
    }
}

// One wave per atom. Prologue: lane k gathers its edge, computes R[0..11]
// (12 exp2) and T[0..8], type-sorts via ballots, writes 21-float record to
// LDS at stride 25 (conflict-free). Edge loop: 4 ds_read_b32 + 2 fma / edge.
__global__ void __launch_bounds__(256)
accum_kernel(const float4* __restrict__ posT,
             const int* __restrict__ cnt,
             const unsigned short* __restrict__ bucket,
             __hip_bfloat16* __restrict__ c2, int N) {
    __shared__ float sE[WPB][64][RSTRIDE];
    int wid = (blockIdx.x * blockDim.x + threadIdx.x) >> 6;
    int lane = threadIdx.x & 63;
    int wslot = (threadIdx.x >> 6);
    if (wid >= N) return;
    int i = wid;

    float4 pi = posT[i];
    int degv = cnt[i];
    degv = degv > BCAP ? BCAP : degv;
    int deg = __builtin_amdgcn_readfirstlane(degv);

    int jv = bucket[(i << 6) + lane];        // coalesced 128B row
    bool valid = lane < deg;
    int jsafe = valid ? jv : i;              // guard stale (poisoned) slots
    float4 pj = posT[jsafe];

    float dx = pj.x - pi.x, dy = pj.y - pi.y, dz = pj.z - pi.z;
    float u  = fmaf(dz, dz, fmaf(dy, dy, fmaf(dx, dx, 1e-12f)));
    float wv = __log2f(u);
    float ir = rsqrtf(u);
    float iu = ir * ir;
    float lf = 0.0f;
    if (u >= 10.89f) {                       // 3.3 <= r < 3.6: taper into exp
        float r = sqrtf(u);
        float fcv = 0.5f + 0.5f * __cosf(10.471975511965978f * (r - 3.3f));
        lf = __log2f(fcv);
    }
    int tj = __float_as_int(pj.w);

    // 12 radials R_n = exp2(0.5n*log2(u) + qc_n*u + lf)
    const float QC[12] = {
        -8.014972449383130f, -8.014972449383130f, -4.007486224691565f,
        -2.671657483127710f, -2.003743112345783f, -1.602994489876626f,
        -1.335828741563855f, -1.144996064197590f, -1.001871556172891f,
        -0.890552494375903f, -0.801497244938313f, -0.728633859034830f };
    float R[12];
    #pragma unroll
    for (int n = 0; n < 12; ++n)
        R[n] = exp2_fast(fmaf(0.5f * n, wv, fmaf(QC[n], u, lf)));

    // type-sort among valid lanes
    ull m0b = __ballot(valid && tj == 0);
    ull m1b = __ballot(valid && tj == 1);
    ull m2b = __ballot(valid && tj == 2);
    ull lt  = (lane == 63) ? 0x7FFFFFFFFFFFFFFFull : ((1ull << lane) - 1ull);
    int c0n = __popcll(m0b);
    int c1n = __popcll(m1b);
    int dest;
    if (!valid)          dest = deg + __popcll(~(m0b | m1b | m2b) & lt);
    else if (tj == 0)    dest = __popcll(m0b & lt);
    else if (tj == 1)    dest = c0n + __popcll(m1b & lt);
    else                 dest = c0n + c1n + __popcll(m2b & lt);

    float* rec = &sE[wslot][dest][0];
    #pragma unroll
    for (int n = 0; n < 12; ++n) rec[n] = R[n];
    rec[12] = 1.0f;
    rec[13] = dy * ir;  rec[14] = dz * ir;  rec[15] = dx * ir;
    rec[16] = dx * dy * iu;
    rec[17] = dy * dz * iu;
    rec[18] = fmaf(dz, dz, -0.33333333333333333f * u) * iu;
    rec[19] = dx * dz * iu;
    rec[20] = fmaf(dx, dx, -(dy * dy)) * iu;
    asm volatile("s_waitcnt lgkmcnt(0)" ::: "memory");

    int e1b = c0n + c1n;                     // scalar (ballot popcounts)

    // per-lane slot indices: slot0 = lane, slot1 = lane+64 (slot = m*12+n)
    int n0 = lane % 12, m0 = lane / 12;
    int idx1 = lane + 64;
    bool has1 = idx1 < 108;
    int i1 = has1 ? idx1 : 0;
    int n1 = i1 % 12, m1 = i1 / 12;

    const float* recb = &sE[wslot][0][0];

    float a00 = 0.f, a01 = 0.f, a02 = 0.f;
    float a10 = 0.f, a11 = 0.f, a12 = 0.f;

    #define EDGE_BODY(E_IDX, ACC0, ACC1)                                   \
    {                                                                      \
        const float* rp = recb + (E_IDX) * RSTRIDE;                        \
        float Rv0 = rp[n0];                                                \
        float Tv0 = rp[12 + m0];                                           \
        float Rv1 = rp[n1];                                                \
        float Tv1 = rp[12 + m1];                                           \
        ACC0 = fmaf(Rv0, Tv0, ACC0);                                       \
        ACC1 = fmaf(Rv1, Tv1, ACC1);                                       \
    }

    int e = 0;
    #pragma unroll 4
    for (; e < c0n; ++e)  EDGE_BODY(e, a00, a10);
    #pragma unroll 4
    for (; e < e1b; ++e)  EDGE_BODY(e, a01, a11);
    #pragma unroll 4
    for (; e < deg; ++e)  EDGE_BODY(e, a02, a12);
    #undef EDGE_BODY

    __hip_bfloat16* cb = c2 + (size_t)i * CPA;
    cb[m0 * 36 + 0 * 12 + n0] = __float2bfloat16(a00);
    cb[m0 * 36 + 1 * 12 + n0] = __float2bfloat16(a01);
    cb[m0 * 36 + 2 * 12 + n0] = __float2bfloat16(a02);
    if (has1) {
        cb[m1 * 36 + 0 * 12 + n1] = __float2bfloat16(a10);
        cb[m1 * 36 + 1 * 12 + n1] = __float2bfloat16(a11);
        cb[m1 * 36 + 2 * 12 + n1] = __float2bfloat16(a12);
    }
}

// Wave = (64 atoms, one m). Rescale v by K_m, add Y00 self-term, v^T A_l v.
__global__ void __launch_bounds__(576)
quad_kernel(const __hip_bfloat16* __restrict__ c2,
            const int* __restrict__ types,
            const float* __restrict__ A,
            float* __restrict__ out, int N) {
    __shared__ float sred[9];
    int m = __builtin_amdgcn_readfirstlane(threadIdx.x >> 6);
    int lane = threadIdx.x & 63;
    int i = blockIdx.x * 64 + lane;
    float dot = 0.0f;
    if (i < N) {
        float Km = m == 0 ? 0.28209479177387814f
                 : (m < 4 ? 0.4886025119029199f
                 : (m == 6 ? 0.94617469575756f
                 : (m == 8 ? 0.5462742152960396f : 1.0925484305920792f)));
        const ushort4v* cb4 =
            (const ushort4v*)(c2 + (size_t)i * CPA + m * 36);
        float v[36];
        #pragma unroll
        for (int q = 0; q < 9; ++q) {
            ushort4v u = cb4[q];
            #pragma unroll
            for (int r = 0; r < 4; ++r)
                v[q * 4 + r] = __uint_as_float(((unsigned)u[r]) << 16) * Km;
        }
        if (m == 0) {
            int ti = types[i];
            const float Y00 = 0.28209479177387814f;
            v[0]  += ti == 0 ? Y00 : 0.f;
            v[12] += ti == 1 ? Y00 : 0.f;
            v[24] += ti == 2 ? Y00 : 0.f;
        }
        int l = (m == 0) ? 0 : (m < 4 ? 1 : 2);
        const float* Al = A + l * 1296;
        #pragma unroll
        for (int an = 0; an < 36; ++an) {
            float s = 0.0f;
            #pragma unroll
            for (int b = 0; b < 36; ++b)
                s = fmaf(Al[an * 36 + b], v[b], s);
            dot = fmaf(v[an], s, dot);
        }
    }
    #pragma unroll
    for (int off = 32; off > 0; off >>= 1) dot += __shfl_down(dot, off, 64);
    if (lane == 0) sred[m] = dot;
    __syncthreads();
    if (threadIdx.x == 0) {
        float s = 0.f;
        #pragma unroll
        for (int kk = 0; kk < 9; ++kk) s += sred[kk];
        atomicAdd(out, s);
    }
}

extern "C" void kernel_launch(void* const* d_in, const int* in_sizes, int n_in,
                              void* d_out, int out_size, void* d_ws, size_t ws_size,
                              hipStream_t stream) {
    const float* pos   = (const float*)d_in[0];
    const float* w     = (const float*)d_in[1];
    const float* bias  = (const float*)d_in[2];
    const int*   types = (const int*)d_in[3];
    const int*   pairs = (const int*)d_in[4];
    float* out = (float*)d_out;

    int N = in_sizes[0] / 3;
    int E = in_sizes[4] / 2;

    char* ws = (char*)d_ws;
    size_t off = 0;
    float* A = (float*)(ws + off);             off += 16384;
    int* cnt = (int*)(ws + off);               off += ((size_t)N * 4 + 255) & ~(size_t)255;
    float4* posT = (float4*)(ws + off);        off += ((size_t)N * 16 + 255) & ~(size_t)255;
    unsigned short* bucket = (unsigned short*)(ws + off);
                                               off += ((size_t)N * BCAP * 2 + 255) & ~(size_t)255;
    __hip_bfloat16* c2 = (__hip_bfloat16*)(ws + off);

    int pblocks = (N + 255) / 256;
    prep_kernel<<<pblocks, 256, 0, stream>>>(w, bias, pos, types, A, posT, cnt, out, N);

    int equads = (E + 3) / 4;
    int eblocks = (equads + 255) / 256;
    build_kernel<<<eblocks, 256, 0, stream>>>(pairs, posT, cnt, bucket, E);

    int ablocks = ((size_t)N * 64 + 255) / 256;
    accum_kernel<<<ablocks, 256, 0, stream>>>(posT, cnt, bucket, c2, N);

    int qblocks = (N + 63) / 64;
    quad_kernel<<<qblocks, 576, 0, stream>>>(c2, types, A, out, N);
}